// Round 1
// 77.559 us; speedup vs baseline: 1.0355x; 1.0355x over previous
//
#include <hip/hip_runtime.h>

// TT-embedding: VOC = 100*100*100, EMB = 4*4*8, RANK = 16, PAD_IDX = 0.
// core0 [1,100,4,16], core1 [16,100,4,16], core2 [16,100,8,1]  (float32)
// x [64,512] int32 indices; out [64,512,128] float32.
//
// emb[j1,j2,j3] = sum_{r1,r2} A(i1)[j1,r1] * B(i2)[r1,j2,r2] * C(i3)[r2,j3]
// Factored: M[r1,j2,j3] = sum_r2 B*C (8192 MAC/token), emb = sum_r1 A*M (2048 MAC/token).
//
// v2: DS-pipe starvation.
//  - idx forced to SGPR (readfirstlane) -> C reads are s_load (constant cache), A reads
//    are per-lane L1 hits. Neither touches LDS (removes ~38 DS instrs/wave).
//  - Ms is wave-private -> no __syncthreads; just s_waitcnt lgkmcnt(0) (lockstep lanes).
//  - Ms lane stride padded 8 -> 12 floats: write slot = (3*lane)&7, bijective per
//    8-lane group -> conflict-free ds_write_b128; reads <=2-way (free).

#define MS_STRIDE 12                      // floats per lane row (pad kills write bank conflicts)
#define LDS_PER_WAVE (64 * MS_STRIDE)     // 768 floats = 3072 B per wave

__global__ __launch_bounds__(256) void tt_embed_kernel(
    const int* __restrict__ x,
    const float* __restrict__ c0,   // [100,4,16]
    const float* __restrict__ c1,   // [16,100,4,16]
    const float* __restrict__ c2,   // [16,100,8]
    float* __restrict__ out,        // [nTok,128]
    int nTok)
{
    __shared__ __align__(16) float lds[4 * LDS_PER_WAVE];   // 12 KiB / block
    const int wave = threadIdx.x >> 6;
    const int lane = threadIdx.x & 63;
    const int t = blockIdx.x * 4 + wave;
    const bool active = (t < nTok);

    float* Ms = lds + wave * LDS_PER_WAVE;

    int idx = 0;
    if (active) idx = x[t];
    // Wave-uniform by construction; make it provably so -> SGPR -> scalar loads below.
    idx = __builtin_amdgcn_readfirstlane(idx);
    const int i1 = idx / 10000;
    const int rem = idx - i1 * 10000;
    const int i2 = rem / 100;
    const int i3 = rem - i2 * 100;

    // ---- This lane's B row: core1[r1, i2, j2, 0..15]  (r1 = lane>>2, j2 = lane&3)
    const int r1 = lane >> 2;
    const int j2 = lane & 3;
    const float4* bp = (const float4*)(c1 + ((r1 * 100 + i2) * 4 + j2) * 16);
    float4 b0 = bp[0], b1 = bp[1], b2 = bp[2], b3 = bp[3];

    // ---- Hoist stage-2's A fragment (c0 is 25 KB, L1-resident; 4 lines/wave, broadcast)
    const int e0 = lane * 2;         // this lane's two adjacent outputs
    const int j1 = e0 >> 5;          // 0..3 (per-lane constant)
    const int mcol = e0 & 31;        // j2*8 + j3, even
    const float4* ap = (const float4*)(c0 + i1 * 64 + j1 * 16);
    float4 a0 = ap[0], a1 = ap[1], a2 = ap[2], a3 = ap[3];

    float bb[16] = { b0.x,b0.y,b0.z,b0.w, b1.x,b1.y,b1.z,b1.w,
                     b2.x,b2.y,b2.z,b2.w, b3.x,b3.y,b3.z,b3.w };

    // ---- Stage 1: M[r1,j2,0..7] = sum_r2 bb[r2] * C[r2,i3,0..7]
    // C addresses are scalar (i3 in SGPR) -> s_load_dwordx* via constant cache.
    float mv[8];
    #pragma unroll
    for (int j = 0; j < 8; ++j) mv[j] = 0.0f;
    const float* Cb = c2 + i3 * 8;
    #pragma unroll
    for (int r2 = 0; r2 < 16; ++r2) {
        const float* cp = Cb + r2 * 800;   // c2[r2, i3, :]
        const float b = bb[r2];
        mv[0] += b * cp[0]; mv[1] += b * cp[1]; mv[2] += b * cp[2]; mv[3] += b * cp[3];
        mv[4] += b * cp[4]; mv[5] += b * cp[5]; mv[6] += b * cp[6]; mv[7] += b * cp[7];
    }

    // ---- Write M to wave-private LDS, padded stride (conflict-free b128 writes)
    {
        float4* mp = (float4*)(Ms + lane * MS_STRIDE);
        mp[0] = make_float4(mv[0], mv[1], mv[2], mv[3]);
        mp[1] = make_float4(mv[4], mv[5], mv[6], mv[7]);
    }

    // Intra-wave producer->consumer only (Ms is wave-private, lanes lockstep):
    // no __syncthreads needed, just drain LDS writes and fence the compiler.
    asm volatile("s_waitcnt lgkmcnt(0)" ::: "memory");

    // ---- Stage 2: out[e0], out[e0+1] = sum_r A[j1,r] * M[r, mcol .. mcol+1]
    float av[16] = { a0.x,a0.y,a0.z,a0.w, a1.x,a1.y,a1.z,a1.w,
                     a2.x,a2.y,a2.z,a2.w, a3.x,a3.y,a3.z,a3.w };

    const int rbase = (mcol >> 3) * MS_STRIDE + (mcol & 7);
    float o0 = 0.0f, o1 = 0.0f;
    #pragma unroll
    for (int r = 0; r < 16; ++r) {
        const float2 m = *(const float2*)(Ms + r * (4 * MS_STRIDE) + rbase);
        o0 += av[r] * m.x;
        o1 += av[r] * m.y;
    }

    if (idx == 0) { o0 = 0.0f; o1 = 0.0f; }   // PAD_IDX -> zero row

    if (active) {
        *(float2*)(out + (long)t * 128 + e0) = make_float2(o0, o1);
    }
}

extern "C" void kernel_launch(void* const* d_in, const int* in_sizes, int n_in,
                              void* d_out, int out_size, void* d_ws, size_t ws_size,
                              hipStream_t stream) {
    const int*   x  = (const int*)d_in[0];
    const float* c0 = (const float*)d_in[1];
    const float* c1 = (const float*)d_in[2];
    const float* c2 = (const float*)d_in[3];
    float* out = (float*)d_out;

    const int nTok = out_size / 128;           // 64*512 = 32768
    const int blocks = (nTok + 3) / 4;         // one wave per token, 4 waves/block
    tt_embed_kernel<<<dim3(blocks), dim3(256), 0, stream>>>(x, c0, c1, c2, out, nTok);
}